// Round 11
// baseline (2245.315 us; speedup 1.0000x reference)
//
#include <hip/hip_runtime.h>
#include <hip/hip_bf16.h>

typedef __attribute__((ext_vector_type(8))) short short8;
typedef __attribute__((ext_vector_type(4))) float f32x4;

#define NQ 95
#define HDIM 512
#define RBF 6
#define BM 64

static __device__ __forceinline__ unsigned short f2bf(float f){
  unsigned u = __float_as_uint(f);
  u += 0x7FFF + ((u >> 16) & 1);          // round-to-nearest-even
  return (unsigned short)(u >> 16);
}
static __device__ __forceinline__ float swishf(float z){
  float e = __expf(-z);
  return z * __builtin_amdgcn_rcpf(1.0f + e);
}

// ---------------------------------------------------------------------------
// P0[v][n] = sum_k emb[v][k] * W_lin[k][n] + b_lin[n];  P1: second 512-block
// ---------------------------------------------------------------------------
__global__ __launch_bounds__(512) void prep_tables(
    const float* __restrict__ emb, const float* __restrict__ W_lin,
    const float* __restrict__ b_lin, float* __restrict__ P0,
    float* __restrict__ P1)
{
  __shared__ float sE[HDIM];
  const int v   = blockIdx.x % NQ;
  const int tab = blockIdx.x / NQ;
  const int t   = threadIdx.x;
  sE[t] = emb[v*HDIM + t];
  __syncthreads();
  const float* W = W_lin + (size_t)tab * HDIM * HDIM + t;
  float a = tab ? 0.f : b_lin[t];
  #pragma unroll 8
  for (int k = 0; k < HDIM; ++k)
    a += sE[k] * W[(size_t)k * HDIM];
  (tab ? P1 : P0)[v*HDIM + t] = a;
}

// ---------------------------------------------------------------------------
// W2T[n][k] = bf16(W_lin[1024+k][n])   (512x512 bf16, n-major)
// ---------------------------------------------------------------------------
__global__ __launch_bounds__(256) void prep_w2t(
    const float* __restrict__ W_lin, unsigned short* __restrict__ W2T)
{
  const int idx = blockIdx.x * 256 + threadIdx.x;
  const int n  = idx >> 6;
  const int kb = (idx & 63) * 8;
  const float* W2 = W_lin + (size_t)1024 * HDIM;
  unsigned p[4];
  #pragma unroll
  for (int c = 0; c < 4; ++c){
    unsigned lo = f2bf(W2[(size_t)(kb + 2*c    ) * HDIM + n]);
    unsigned hi = f2bf(W2[(size_t)(kb + 2*c + 1) * HDIM + n]);
    p[c] = lo | (hi << 16);
  }
  uint4 o; o.x = p[0]; o.y = p[1]; o.z = p[2]; o.w = p[3];
  *(uint4*)(W2T + (size_t)n * HDIM + kb) = o;
}

// ---------------------------------------------------------------------------
// W1T32[n][k] = bf16(W1[k][n]) for k<6, else 0   (512x32 bf16, n-major)
// B-operand for the K=32 g-MFMA.
// ---------------------------------------------------------------------------
__global__ __launch_bounds__(256) void prep_w1t(
    const float* __restrict__ W1, unsigned short* __restrict__ W1T32)
{
  const int n = blockIdx.x * 256 + threadIdx.x;   // 0..511
  unsigned short row[32];
  #pragma unroll
  for (int k = 0; k < 32; ++k) row[k] = 0;
  #pragma unroll
  for (int r = 0; r < RBF; ++r) row[r] = f2bf(W1[r*HDIM + n]);
  #pragma unroll
  for (int c = 0; c < 4; ++c)
    *(short8*)(W1T32 + (size_t)n*32 + c*8) = *(const short8*)(row + c*8);
}

// ---------------------------------------------------------------------------
// Fused main kernel: 512 threads (8 waves), BM=64 edges/block, 2 blocks/CU.
//   phase 1: A = bf16(swish(rbf@W0+b0)) [64][512] LDS (XOR swizzle) +
//            rbf32 [64][32] bf16 LDS tile (K-padded rbf for g-MFMA).
//   then per wave, 2 column-passes (32 cols each), NO further barriers:
//     K-loop (16 ks, acc[4][2]) -> g via 1 MFMA K=32 per 16-col tile ->
//     direct scalar stores. Stores spread across the block; waves drift.
// ---------------------------------------------------------------------------
__global__ __launch_bounds__(512, 4) void fused_edge(
    const int* __restrict__ xv, const float* __restrict__ rbf,
    const int* __restrict__ ei, const int* __restrict__ ej,
    const float* __restrict__ W0, const float* __restrict__ b0,
    const float* __restrict__ P0, const float* __restrict__ P1,
    const unsigned short* __restrict__ W2T,
    const unsigned short* __restrict__ W1T32,
    float* __restrict__ out, int E)
{
  __shared__ unsigned short sA[BM * HDIM];       // 64 KB
  __shared__ unsigned short sRbf32[BM * 32];     // 4 KB
  __shared__ float sRbf[BM * RBF];
  __shared__ int sXi[BM], sXj[BM];

  const int t  = threadIdx.x;
  const int eb = blockIdx.x * BM;
  const int me = min(BM, E - eb);

  // ---- stage rbf rows + node-type indices ----
  if (t < 96){
    float4 v = make_float4(0.f, 0.f, 0.f, 0.f);
    size_t gi  = (size_t)eb * RBF + (size_t)t * 4;
    size_t lim = (size_t)E * RBF;
    if (gi + 4 <= lim) v = *(const float4*)(rbf + gi);
    else {
      float* pv = (float*)&v;
      for (int c = 0; c < 4; ++c) if (gi + c < lim) pv[c] = rbf[gi + c];
    }
    *(float4*)(sRbf + t*4) = v;
  } else if (t >= 128 && t < 192){
    int q = t - 128;
    int xi = 0, xj = 0;
    int e = eb + q;
    if (e < E){ xi = xv[ei[e]]; xj = xv[ej[e]]; }
    sXi[q] = xi; sXj[q] = xj;
  }

  // phase-1 assignment: 256 col-pairs x 2 row-halves
  const int cp   = t & 255;        // k-pair: cols 2cp, 2cp+1
  const int half = t >> 8;         // rows half*32 .. half*32+31
  float2 w0c[RBF];
  #pragma unroll
  for (int r = 0; r < RBF; ++r) w0c[r] = *(const float2*)(W0 + r*HDIM + 2*cp);
  float2 bb = *(const float2*)(b0 + 2*cp);

  __syncthreads();

  char* sAb = (char*)sA;
  // ---- phase 1: rbf0 A-tile (+ rbf32 tile by threads < 256) ----
  {
    const int swz_t = 4 * cp;
    const int m0 = half * 32;
    #pragma unroll 2
    for (int mm = 0; mm < 32; ++mm){
      const int m = m0 + mm;
      float2 ra = *(const float2*)(sRbf + m*RBF);
      float2 rb = *(const float2*)(sRbf + m*RBF + 2);
      float2 rc = *(const float2*)(sRbf + m*RBF + 4);
      float z0 = bb.x, z1 = bb.y;
      z0 += ra.x*w0c[0].x + ra.y*w0c[1].x + rb.x*w0c[2].x
          + rb.y*w0c[3].x + rc.x*w0c[4].x + rc.y*w0c[5].x;
      z1 += ra.x*w0c[0].y + ra.y*w0c[1].y + rb.x*w0c[2].y
          + rb.y*w0c[3].y + rc.x*w0c[4].y + rc.y*w0c[5].y;
      __hip_bfloat162 hb = __float22bfloat162_rn(make_float2(swishf(z0), swishf(z1)));
      unsigned pk = *reinterpret_cast<unsigned*>(&hb);
      *(unsigned*)(sAb + (m*1024 + (swz_t ^ ((m & 7) << 4)))) = pk;
    }
    if (t < 256){
      const int row = t >> 2, kb = (t & 3) * 8;
      unsigned short v[8];
      #pragma unroll
      for (int j = 0; j < 8; ++j){
        int k = kb + j;
        v[j] = (k < RBF) ? f2bf(sRbf[row*RBF + k]) : (unsigned short)0;
      }
      *(short8*)(sRbf32 + row*32 + kb) = *(const short8*)v;
    }
  }
  __syncthreads();
  // ---- no more barriers: A-tile and rbf32 are read-only from here ----

  const int lane  = t & 63;
  const int w     = t >> 6;
  const int nbase = w * 64;
  const int rlo   = lane & 15;
  const int kg    = lane >> 4;

  float* __restrict__ out2 = out + (size_t)E * HDIM;
  const f32x4 zero4 = {0.f, 0.f, 0.f, 0.f};

  // g A-fragments (shared by both passes): rbf32[mt*16+rlo][kg*8..+8]
  short8 ga[4];
  #pragma unroll
  for (int mt = 0; mt < 4; ++mt)
    ga[mt] = *(const short8*)(sRbf32 + (mt*16 + rlo)*32 + kg*8);

  #pragma unroll 1
  for (int np = 0; np < 2; ++np){
    const int ncol0 = nbase + np*32;           // 32-col slice of this pass

    // ---- K-loop: acc[4][2] over 16 K-steps ----
    f32x4 acc[4][2];
    #pragma unroll
    for (int a = 0; a < 4; ++a){ acc[a][0] = zero4; acc[a][1] = zero4; }

    const unsigned short* bpA = W2T + (size_t)(ncol0 + rlo)*HDIM + kg*8;
    const unsigned short* bpB = bpA + (size_t)16*HDIM;

    for (int ks = 0; ks < 16; ++ks){
      short8 b0r = *(const short8*)(bpA + ks*32);
      short8 b1r = *(const short8*)(bpB + ks*32);
      #pragma unroll
      for (int mt = 0; mt < 4; ++mt){
        int row = mt*16 + rlo;
        int off = row*1024 + ((ks*64 + kg*16) ^ ((row & 7) << 4));
        short8 af = *(const short8*)(sAb + off);
        acc[mt][0] = __builtin_amdgcn_mfma_f32_16x16x32_bf16(af, b0r, acc[mt][0], 0, 0, 0);
        acc[mt][1] = __builtin_amdgcn_mfma_f32_16x16x32_bf16(af, b1r, acc[mt][1], 0, 0, 0);
      }
    }

    // ---- per 16-col tile: g-MFMA then direct stores ----
    #pragma unroll
    for (int nt = 0; nt < 2; ++nt){
      const int n = ncol0 + nt*16 + rlo;
      short8 gb = *(const short8*)(W1T32 + (size_t)n*32 + kg*8);
      f32x4 accg[4];
      #pragma unroll
      for (int mt = 0; mt < 4; ++mt)
        accg[mt] = __builtin_amdgcn_mfma_f32_16x16x32_bf16(ga[mt], gb, zero4, 0, 0, 0);

      #pragma unroll
      for (int mt = 0; mt < 4; ++mt){
        #pragma unroll
        for (int r = 0; r < 4; ++r){
          const int m = mt*16 + kg*4 + r;
          if (m < me){
            const float p0v = P0[(size_t)sXi[m]*HDIM + n];
            const float p1v = P1[(size_t)sXj[m]*HDIM + n];
            const float f   = acc[mt][nt][r] + p0v + p1v;
            const float e1  = swishf(f);
            const size_t o  = (size_t)(eb + m)*HDIM + n;
            out[o]  = e1;
            out2[o] = accg[mt][r] * e1;
          }
        }
      }
    }
  }
}

// ---------------------------------------------------------------------------
extern "C" void kernel_launch(void* const* d_in, const int* in_sizes, int n_in,
                              void* d_out, int out_size, void* d_ws, size_t ws_size,
                              hipStream_t stream) {
  const int*   xv    = (const int*)  d_in[0];
  const float* rbf   = (const float*)d_in[1];
  const int*   ei    = (const int*)  d_in[2];
  const int*   ej    = (const int*)  d_in[3];
  const float* emb   = (const float*)d_in[4];
  const float* W0    = (const float*)d_in[5];
  const float* b0    = (const float*)d_in[6];
  const float* W_lin = (const float*)d_in[7];
  const float* b_lin = (const float*)d_in[8];
  const float* W1    = (const float*)d_in[9];
  float* out = (float*)d_out;

  const int E = in_sizes[2];

  float* P0 = (float*)d_ws;
  float* P1 = P0 + NQ * HDIM;
  unsigned short* W2T   = (unsigned short*)(P1 + NQ * HDIM);
  unsigned short* W1T32 = W2T + (size_t)HDIM * HDIM;

  prep_tables<<<2 * NQ, 512, 0, stream>>>(emb, W_lin, b_lin, P0, P1);
  prep_w2t<<<(HDIM * (HDIM/8)) / 256, 256, 0, stream>>>(W_lin, W2T);
  prep_w1t<<<2, 256, 0, stream>>>(W1, W1T32);

  const int nblk = (E + BM - 1) / BM;
  fused_edge<<<nblk, 512, 0, stream>>>(xv, rbf, ei, ej, W0, b0,
                                       P0, P1, W2T, W1T32, out, E);
}

// Round 12
// 508.052 us; speedup vs baseline: 4.4195x; 4.4195x over previous
//
#include <hip/hip_runtime.h>
#include <hip/hip_bf16.h>

typedef __attribute__((ext_vector_type(8))) short short8;
typedef __attribute__((ext_vector_type(4))) float f32x4;

#define NQ 95
#define HDIM 512
#define RBF 6
#define BM 128

static __device__ __forceinline__ unsigned short f2bf(float f){
  unsigned u = __float_as_uint(f);
  u += 0x7FFF + ((u >> 16) & 1);          // round-to-nearest-even
  return (unsigned short)(u >> 16);
}
static __device__ __forceinline__ float swishf(float z){
  float e = __expf(-z);
  return z * __builtin_amdgcn_rcpf(1.0f + e);
}

// ---------------------------------------------------------------------------
// P0[v][n] = sum_k emb[v][k] * W_lin[k][n] + b_lin[n];  P1: second 512-block
// ---------------------------------------------------------------------------
__global__ __launch_bounds__(512) void prep_tables(
    const float* __restrict__ emb, const float* __restrict__ W_lin,
    const float* __restrict__ b_lin, float* __restrict__ P0,
    float* __restrict__ P1)
{
  __shared__ float sE[HDIM];
  const int v   = blockIdx.x % NQ;
  const int tab = blockIdx.x / NQ;
  const int t   = threadIdx.x;
  sE[t] = emb[v*HDIM + t];
  __syncthreads();
  const float* W = W_lin + (size_t)tab * HDIM * HDIM + t;
  float a = tab ? 0.f : b_lin[t];
  #pragma unroll 8
  for (int k = 0; k < HDIM; ++k)
    a += sE[k] * W[(size_t)k * HDIM];
  (tab ? P1 : P0)[v*HDIM + t] = a;
}

// ---------------------------------------------------------------------------
// W2T[n][k] = bf16(W_lin[1024+k][n])   (512x512 bf16, n-major)
// ---------------------------------------------------------------------------
__global__ __launch_bounds__(256) void prep_w2t(
    const float* __restrict__ W_lin, unsigned short* __restrict__ W2T)
{
  const int idx = blockIdx.x * 256 + threadIdx.x;
  const int n  = idx >> 6;
  const int kb = (idx & 63) * 8;
  const float* W2 = W_lin + (size_t)1024 * HDIM;
  unsigned p[4];
  #pragma unroll
  for (int c = 0; c < 4; ++c){
    unsigned lo = f2bf(W2[(size_t)(kb + 2*c    ) * HDIM + n]);
    unsigned hi = f2bf(W2[(size_t)(kb + 2*c + 1) * HDIM + n]);
    p[c] = lo | (hi << 16);
  }
  uint4 o; o.x = p[0]; o.y = p[1]; o.z = p[2]; o.w = p[3];
  *(uint4*)(W2T + (size_t)n * HDIM + kb) = o;
}

// ---------------------------------------------------------------------------
// Fused main kernel (R10 structure + XCD-bijective block swizzle).
//   1024 threads (16 waves), BM=128 edges/block, 1 block/CU.
//   phase 1: A = bf16(swish(rbf@W0+b0)) [128x512] in LDS (XOR swizzle, 128KB)
//   phase 2: acc = A @ W2T, wave tile 128 rows x 32 cols (acc[8][2])
//   epilogue: 4 chunks x 32 rows — scatter raw acc into dead A-tile LDS,
//     then column-contiguous sweep (full-line f32x4 stores only; R11 showed
//     partial-line scalar stores cause 3x HBM write amplification).
//   Swizzle: each XCD owns a contiguous 1/8 of edge tiles -> linear L2
//     writeback streams per XCD (T1, m204 bijective form).
// ---------------------------------------------------------------------------
__global__ __launch_bounds__(1024, 4) void fused_edge(
    const int* __restrict__ xv, const float* __restrict__ rbf,
    const int* __restrict__ ei, const int* __restrict__ ej,
    const float* __restrict__ W0, const float* __restrict__ b0,
    const float* __restrict__ W1,
    const float* __restrict__ P0, const float* __restrict__ P1,
    const unsigned short* __restrict__ W2T,
    float* __restrict__ out, int E, int nblk)
{
  __shared__ unsigned short sA[BM * HDIM];   // 128 KB
  __shared__ float sRbf[BM * RBF];
  __shared__ int sXi[BM], sXj[BM];

  const int t  = threadIdx.x;
  // ---- XCD-bijective swizzle: dispatch d (XCD = d%8) -> contiguous chunk ----
  {
  }
  const int q8 = nblk >> 3, r8 = nblk & 7;
  const int xcd = blockIdx.x & 7, lid = blockIdx.x >> 3;
  const int swz = (xcd < r8) ? xcd*(q8+1) + lid
                             : r8*(q8+1) + (xcd - r8)*q8 + lid;
  const int eb = swz * BM;
  const int me = min(BM, E - eb);

  // ---- stage rbf rows (128*6 = 192 float4) + node-type indices ----
  if (t < 192){
    float4 v = make_float4(0.f, 0.f, 0.f, 0.f);
    size_t gi  = (size_t)eb * RBF + (size_t)t * 4;
    size_t lim = (size_t)E * RBF;
    if (gi + 4 <= lim) v = *(const float4*)(rbf + gi);
    else {
      float* pv = (float*)&v;
      for (int c = 0; c < 4; ++c) if (gi + c < lim) pv[c] = rbf[gi + c];
    }
    *(float4*)(sRbf + t*4) = v;
  } else if (t >= 256 && t < 384){
    int q = t - 256;
    int xi = 0, xj = 0;
    int e = eb + q;
    if (e < E){ xi = xv[ei[e]]; xj = xv[ej[e]]; }
    sXi[q] = xi; sXj[q] = xj;
  }

  // phase-1 assignment: 256 col-pairs x 4 row-quarters (32 rows each)
  const int cp = t & 255;          // k-pair: cols 2cp, 2cp+1
  const int q4 = t >> 8;           // rows q4*32 .. q4*32+31
  float2 w0c[RBF];
  #pragma unroll
  for (int r = 0; r < RBF; ++r) w0c[r] = *(const float2*)(W0 + r*HDIM + 2*cp);
  float2 bb = *(const float2*)(b0 + 2*cp);

  __syncthreads();

  char* sAb = (char*)sA;
  // ---- phase 1: rbf0 tile ----
  {
    const int swz_t = 4 * cp;
    const int m0 = q4 * 32;
    #pragma unroll 2
    for (int mm = 0; mm < 32; ++mm){
      const int m = m0 + mm;
      float2 ra = *(const float2*)(sRbf + m*RBF);
      float2 rb = *(const float2*)(sRbf + m*RBF + 2);
      float2 rc = *(const float2*)(sRbf + m*RBF + 4);
      float z0 = bb.x, z1 = bb.y;
      z0 += ra.x*w0c[0].x + ra.y*w0c[1].x + rb.x*w0c[2].x
          + rb.y*w0c[3].x + rc.x*w0c[4].x + rc.y*w0c[5].x;
      z1 += ra.x*w0c[0].y + ra.y*w0c[1].y + rb.x*w0c[2].y
          + rb.y*w0c[3].y + rc.x*w0c[4].y + rc.y*w0c[5].y;
      unsigned pk = (unsigned)f2bf(swishf(z0)) | ((unsigned)f2bf(swishf(z1)) << 16);
      *(unsigned*)(sAb + (m*1024 + (swz_t ^ ((m & 7) << 4)))) = pk;
    }
  }
  __syncthreads();

  // ---- phase 2: MFMA K-loop (wave tile: 128 rows x 32 cols) ----
  const int lane  = t & 63;
  const int w     = t >> 6;        // 0..15
  const int nbase = w * 32;
  const int rlo   = lane & 15;
  const int kg    = lane >> 4;

  f32x4 acc[8][2];
  #pragma unroll
  for (int a = 0; a < 8; ++a)
    #pragma unroll
    for (int b = 0; b < 2; ++b) acc[a][b] = f32x4{0.f, 0.f, 0.f, 0.f};

  const unsigned short* bp0 = W2T + (size_t)(nbase + rlo)*HDIM + kg*8;
  const unsigned short* bp1 = bp0 + (size_t)16*HDIM;

  for (int ks = 0; ks < 16; ++ks){
    short8 b0r = *(const short8*)(bp0 + ks*32);
    short8 b1r = *(const short8*)(bp1 + ks*32);
    #pragma unroll
    for (int mt = 0; mt < 8; ++mt){
      int row = mt*16 + rlo;
      int off = row*1024 + ((ks*64 + kg*16) ^ ((row & 7) << 4));
      short8 af = *(const short8*)(sAb + off);
      acc[mt][0] = __builtin_amdgcn_mfma_f32_16x16x32_bf16(af, b0r, acc[mt][0], 0, 0, 0);
      acc[mt][1] = __builtin_amdgcn_mfma_f32_16x16x32_bf16(af, b1r, acc[mt][1], 0, 0, 0);
    }
  }

  __syncthreads();   // all waves done reading the A-tile -> sA is dead

  // ---- epilogue: 4 chunks x 32 rows; acc-repack; coalesced sweep ----
  float* sF = (float*)sA;              // 32 x 512 f32 = 64 KB (in dead A-tile)
  const int n0  = (4*t) & (HDIM - 1);  // fixed 4 output columns per thread
  const int rad = t >> 7;              // 0..7 (8 rows per sweep pass)

  f32x4 w1v[RBF];
  #pragma unroll
  for (int r = 0; r < RBF; ++r) w1v[r] = *(const f32x4*)(W1 + r*HDIM + n0);
  float* __restrict__ out2 = out + (size_t)E * HDIM;

  #pragma unroll
  for (int c = 0; c < 4; ++c){
    if (c) __syncthreads();            // prev sweep done reading sF
    // scatter: raw acc of rows 32c..32c+31 into sF (fragment layout write)
    #pragma unroll
    for (int mi = 0; mi < 2; ++mi){
      #pragma unroll
      for (int r = 0; r < 4; ++r){
        const int lr = mi*16 + kg*4 + r;       // local row 0..31
        #pragma unroll
        for (int nt = 0; nt < 2; ++nt){
          const int n = nbase + nt*16 + rlo;
          sF[lr*HDIM + n] = acc[2*c + mi][nt][r];
        }
      }
    }
    __syncthreads();
    // sweep: thread owns 4 contiguous cols of 8 rows per pass
    #pragma unroll
    for (int j = 0; j < 4; ++j){
      const int lm = j*8 + rad;
      const int m  = c*32 + lm;
      const bool valid = (m < me);
      const int xi = sXi[m], xj = sXj[m];      // wave-uniform row indices
      f32x4 a  = *(const f32x4*)(sF + lm*HDIM + n0);
      f32x4 p0 = *(const f32x4*)(P0 + (size_t)xi*HDIM + n0);
      f32x4 p1 = *(const f32x4*)(P1 + (size_t)xj*HDIM + n0);
      f32x4 f  = (a + p0) + p1;
      f32x4 e1;
      e1.x = swishf(f.x); e1.y = swishf(f.y);
      e1.z = swishf(f.z); e1.w = swishf(f.w);
      float2 ra = *(const float2*)(sRbf + m*RBF);
      float2 rb = *(const float2*)(sRbf + m*RBF + 2);
      float2 rc = *(const float2*)(sRbf + m*RBF + 4);
      f32x4 g;
      g.x = ra.x*w1v[0].x + ra.y*w1v[1].x + rb.x*w1v[2].x
          + rb.y*w1v[3].x + rc.x*w1v[4].x + rc.y*w1v[5].x;
      g.y = ra.x*w1v[0].y + ra.y*w1v[1].y + rb.x*w1v[2].y
          + rb.y*w1v[3].y + rc.x*w1v[4].y + rc.y*w1v[5].y;
      g.z = ra.x*w1v[0].z + ra.y*w1v[1].z + rb.x*w1v[2].z
          + rb.y*w1v[3].z + rc.x*w1v[4].z + rc.y*w1v[5].z;
      g.w = ra.x*w1v[0].w + ra.y*w1v[1].w + rb.x*w1v[2].w
          + rb.y*w1v[3].w + rc.x*w1v[4].w + rc.y*w1v[5].w;
      f32x4 e2 = g * e1;
      if (valid){
        const size_t orow = (size_t)(eb + m) * HDIM + n0;
        *(f32x4*)(out  + orow) = e1;
        *(f32x4*)(out2 + orow) = e2;
      }
    }
  }
}

// ---------------------------------------------------------------------------
extern "C" void kernel_launch(void* const* d_in, const int* in_sizes, int n_in,
                              void* d_out, int out_size, void* d_ws, size_t ws_size,
                              hipStream_t stream) {
  const int*   xv    = (const int*)  d_in[0];
  const float* rbf   = (const float*)d_in[1];
  const int*   ei    = (const int*)  d_in[2];
  const int*   ej    = (const int*)  d_in[3];
  const float* emb   = (const float*)d_in[4];
  const float* W0    = (const float*)d_in[5];
  const float* b0    = (const float*)d_in[6];
  const float* W_lin = (const float*)d_in[7];
  const float* b_lin = (const float*)d_in[8];
  const float* W1    = (const float*)d_in[9];
  float* out = (float*)d_out;

  const int E = in_sizes[2];

  float* P0 = (float*)d_ws;
  float* P1 = P0 + NQ * HDIM;
  unsigned short* W2T = (unsigned short*)(P1 + NQ * HDIM);

  prep_tables<<<2 * NQ, 512, 0, stream>>>(emb, W_lin, b_lin, P0, P1);
  prep_w2t<<<(HDIM * (HDIM/8)) / 256, 256, 0, stream>>>(W_lin, W2T);

  const int nblk = (E + BM - 1) / BM;
  fused_edge<<<nblk, 1024, 0, stream>>>(xv, rbf, ei, ej, W0, b0, W1,
                                        P0, P1, W2T, out, E, nblk);
}